// Round 8
// baseline (12148.907 us; speedup 1.0000x reference)
//
#include <hip/hip_runtime.h>
#include <math.h>

#define TT 2048
#define II 64
#define HH 512
#define LL 5
#define RING 16
#define BPL 32                // blocks per layer
#define NBLK (LL * BPL)       // 160
#define WPB 16                // waves per block
#define SPIN_LIMIT 2000000L

typedef unsigned long long u64;
typedef unsigned u32;

__device__ __forceinline__ float wave_sum(float v) {
#pragma unroll
  for (int m = 32; m > 0; m >>= 1) v += __shfl_xor(v, m, 64);
  return v;
}

__device__ __forceinline__ float wave_max(float v) {
#pragma unroll
  for (int m = 32; m > 0; m >>= 1) v = fmaxf(v, __shfl_xor(v, m, 64));
  return v;
}

__device__ __forceinline__ float sigmoidf_(float v) {
  return 1.0f / (1.0f + expf(-v));
}

// MALL-coherent (agent-scope relaxed) accessors — proven transport (r3/r5/r7)
__device__ __forceinline__ u32 ld4(const u32* p) {
  return __hip_atomic_load((u32*)p, __ATOMIC_RELAXED, __HIP_MEMORY_SCOPE_AGENT);
}
__device__ __forceinline__ void st4(u32* p, u32 v) {
  __hip_atomic_store(p, v, __ATOMIC_RELAXED, __HIP_MEMORY_SCOPE_AGENT);
}
__device__ __forceinline__ u64 ld8(const u64* p) {
  return __hip_atomic_load((u64*)p, __ATOMIC_RELAXED, __HIP_MEMORY_SCOPE_AGENT);
}
__device__ __forceinline__ void st8(u64* p, u64 v) {
  __hip_atomic_store(p, v, __ATOMIC_RELAXED, __HIP_MEMORY_SCOPE_AGENT);
}

// 4-deep staggered poll: keep 4 tag loads in flight; check only the oldest so
// the compiler can wait at vmcnt(3). Sample period ~ RTT/4 instead of ~RTT.
__device__ __forceinline__ float poll_ring(const u64* p, u32 want) {
  u64 v0 = ld8(p), v1 = ld8(p), v2 = ld8(p), v3 = ld8(p);
  long sp = 0;
  while ((u32)(v0 >> 32) != want) {
    if (++sp > SPIN_LIMIT) { v0 = 0; break; }  // degrade to wrong-answer, no hang
    v0 = v1; v1 = v2; v2 = v3; v3 = ld8(p);
  }
  return __uint_as_float((u32)v0);
}

__device__ __forceinline__ void wait_ge(u32* p, u32 v) {
  long spins = 0;
  while (ld4(p) < v) {
    if (++spins > SPIN_LIMIT) {
      __hip_atomic_fetch_max(p, v, __ATOMIC_RELAXED, __HIP_MEMORY_SCOPE_AGENT);
      break;
    }
  }
}

// Monotone full-grid barrier — readout phase transitions only (3 uses).
__device__ __forceinline__ void grid_barrier(u32* arrive, u32* gen, u32 idx) {
  __syncthreads();
  if (threadIdx.x == 0) {
    __threadfence();  // release
    u32 target = (u32)NBLK * (idx + 1u);
    u32 prev = __hip_atomic_fetch_add(arrive, 1u, __ATOMIC_RELAXED, __HIP_MEMORY_SCOPE_AGENT);
    if (prev + 1u == target) {
      __hip_atomic_store(gen, idx + 1u, __ATOMIC_RELAXED, __HIP_MEMORY_SCOPE_AGENT);
    } else {
      wait_ge(gen, idx + 1u);
    }
    __threadfence();  // acquire
  }
  __syncthreads();
}

extern "C" __global__ void __launch_bounds__(1024)
__attribute__((amdgpu_waves_per_eu(4, 4)))
lstm_pipe(
    const float* __restrict__ x,
    const float* __restrict__ w_ih0, const float* __restrict__ w_hh0,
    const float* __restrict__ b_ih0, const float* __restrict__ b_hh0,
    const float* __restrict__ w_ih, const float* __restrict__ w_hh,
    const float* __restrict__ b_ih, const float* __restrict__ b_hh,
    const float* __restrict__ w_lin, const float* __restrict__ b_lin,
    float* __restrict__ out, float* __restrict__ ws) {
  extern __shared__ float wihs[];   // [WPB][4][HH] = 128 KB dynamic
  __shared__ float hbuf[2][HH];     // double-buffered staged own-layer h_{t-1}
  __shared__ float xbuf[2][HH];     // double-buffered staged prev-layer h_t / x_t
  __shared__ float sbuf[20];

  // counters (first 4 KB of ws, memset 0): prog[l] at cnt[l*64];
  // garr at cnt[320]; ggen at cnt[336]
  u32* cnt = (u32*)ws;
  u32* garr = cnt + 320;
  u32* ggen = cnt + 336;

  // tagged h ring: [LL][RING][HH] u64 — (tag=t+1)<<32 | bits(h).
  u64* ring = (u64*)((char*)ws + 4096);
  float* h4 = (float*)(ring + (size_t)LL * RING * HH);   // TT*HH
  float* h4T = h4 + (size_t)TT * HH;                     // HH*TT
  float* scores = h4T + (size_t)HH * TT;                 // TT
  float* pbuf = scores + TT;                             // TT
  float* red = pbuf + TT;                                // 1

  const int b = blockIdx.x;
  const int tid = threadIdx.x;
  const int wv = tid >> 6;
  const int lane = tid & 63;
  const int layer = b / BPL;
  const int slot = b % BPL;
  const int j = slot * WPB + wv;   // h-output owned by this wave
  const bool is_last = (layer == LL - 1);

  u32* prog_l = cnt + layer * 64;
  u32* prog_lp1 = cnt + (layer + 1) * 64;  // valid only when layer < LL-1
  u64* myring = ring + (size_t)layer * RING * HH;
  u64* prevring = ring + (size_t)(layer > 0 ? layer - 1 : 0) * RING * HH;

  // ---- weights: whh + bias in registers (fits: ~60 VGPR in r7); wih in LDS ----
  float whh[4][8], bias[4];
  {
    const float* WHH = (layer == 0) ? w_hh0 : (w_hh + (size_t)(layer - 1) * 4 * HH * HH);
#pragma unroll
    for (int g = 0; g < 4; ++g) {
      const int row = g * HH + j;
#pragma unroll
      for (int m = 0; m < 8; ++m) whh[g][m] = WHH[(size_t)row * HH + m * 64 + lane];
    }
    if (layer == 0) {
#pragma unroll
      for (int g = 0; g < 4; ++g) bias[g] = b_ih0[g * HH + j] + b_hh0[g * HH + j];
    } else {
      const float* BIH = b_ih + (size_t)(layer - 1) * 4 * HH;
      const float* BHH = b_hh + (size_t)(layer - 1) * 4 * HH;
#pragma unroll
      for (int g = 0; g < 4; ++g) bias[g] = BIH[g * HH + j] + BHH[g * HH + j];
    }
    // wih -> LDS, layout [jj][g][k]
    const float* WIH = (layer == 0) ? (const float*)0
                                    : (w_ih + (size_t)(layer - 1) * 4 * HH * HH);
    for (int f = tid; f < WPB * 4 * HH; f += 1024) {
      const int jj = f >> 11;          // /2048
      const int g = (f >> 9) & 3;
      const int k = f & 511;
      const int row = g * HH + slot * WPB + jj;
      float v;
      if (layer == 0) v = (k < II) ? w_ih0[(size_t)row * II + k] : 0.0f;
      else v = WIH[(size_t)row * HH + k];
      wihs[f] = v;
    }
    // pin whh/bias (defeat load-rematerialization)
#pragma unroll
    for (int g = 0; g < 4; ++g) {
#pragma unroll
      for (int m = 0; m < 8; ++m) asm volatile("" : "+v"(whh[g][m]));
      asm volatile("" : "+v"(bias[g]));
    }
  }
  __syncthreads();

  float c = 0.0f;

  // ---- recurrence: dbuf staging, pipelined tag poll, ONE sync per step ----
  for (int t = 0; t < TT; ++t) {
    const int ph = t & 1;
    const int sl = t & (RING - 1);
    // staging: threads 0..511 pull own h_{t-1}; 512..1023 pull input h_t / x_t
    if (tid < HH) {
      if (t > 0) {
        hbuf[ph][tid] =
            poll_ring(myring + (size_t)((t - 1) & (RING - 1)) * HH + tid, (u32)t);
      } else {
        hbuf[ph][tid] = 0.0f;
      }
      if (tid == 0) {
        // consumption proof: publishing t means this layer fully staged t-1
        if (slot == 0 && t > 0) st4(prog_l, (u32)t);
        // back-pressure: our step-t store overwrites tag t-15; need layer+1
        // to have consumed it (prog >= t-15)
        if (layer < LL - 1 && t >= RING) {
          long sp = 0;
          while (ld4(prog_lp1) < (u32)(t - (RING - 1)) && ++sp < SPIN_LIMIT) {}
        }
      }
    } else {
      const int k = tid - HH;
      if (layer == 0) {
        xbuf[ph][k] = (k < II) ? x[(size_t)t * II + k] : 0.0f;
      } else {
        xbuf[ph][k] = poll_ring(prevring + (size_t)sl * HH + k, (u32)(t + 1));
      }
    }
    __syncthreads();  // the ONLY per-step barrier (dbuf protects the other side)

    // compute — identical FMA/reduction order to r7 (absmax 0)
    float hp[8], xin[8];
#pragma unroll
    for (int m = 0; m < 8; ++m) {
      hp[m] = hbuf[ph][m * 64 + lane];
      xin[m] = xbuf[ph][m * 64 + lane];
    }
    float ai = 0.0f, af = 0.0f, ag = 0.0f, ao = 0.0f;
#pragma unroll
    for (int m = 0; m < 8; ++m) {
      ai = fmaf(whh[0][m], hp[m], ai);
      af = fmaf(whh[1][m], hp[m], af);
      ag = fmaf(whh[2][m], hp[m], ag);
      ao = fmaf(whh[3][m], hp[m], ao);
    }
    const float* wb = wihs + (size_t)wv * 4 * HH;
#pragma unroll
    for (int m = 0; m < 8; ++m) {
      const int o = m * 64 + lane;
      ai = fmaf(wb[0 * HH + o], xin[m], ai);
      af = fmaf(wb[1 * HH + o], xin[m], af);
      ag = fmaf(wb[2 * HH + o], xin[m], ag);
      ao = fmaf(wb[3 * HH + o], xin[m], ao);
    }
    ai = wave_sum(ai); af = wave_sum(af); ag = wave_sum(ag); ao = wave_sum(ao);
    float gi = sigmoidf_(ai + bias[0]);
    float gf = sigmoidf_(af + bias[1]);
    float gg = tanhf(ag + bias[2]);
    float go = sigmoidf_(ao + bias[3]);
    c = gf * c + gi * gg;
    float h = go * tanhf(c);

    if (lane == 0) {
      st8(myring + (size_t)sl * HH + j,
          (((u64)(u32)(t + 1)) << 32) | (u64)__float_as_uint(h));
      if (is_last) {
        h4[(size_t)t * HH + j] = h;
        h4T[(size_t)j * TT + t] = h;
      }
    }
    // no trailing barrier: next step's staging writes buf[ph^1]; tag polls
    // bound inter-wave skew to one step
  }

  grid_barrier(garr, ggen, 0u);

  // ---- phase A: scores[t] = tanh(h4[t] . w_lin + b_lin) ----
  {
    const int gw = b * WPB + wv;
    if (gw < TT) {
      const int t = gw;
      const float4* hp4 = (const float4*)(h4 + (size_t)t * HH + lane * 8);
      const float4* wl4 = (const float4*)(w_lin + lane * 8);
      float4 a = hp4[0], d = hp4[1], wa = wl4[0], wd = wl4[1];
      float acc = 0.0f;
      acc = fmaf(a.x, wa.x, acc); acc = fmaf(a.y, wa.y, acc);
      acc = fmaf(a.z, wa.z, acc); acc = fmaf(a.w, wa.w, acc);
      acc = fmaf(d.x, wd.x, acc); acc = fmaf(d.y, wd.y, acc);
      acc = fmaf(d.z, wd.z, acc); acc = fmaf(d.w, wd.w, acc);
      acc = wave_sum(acc);
      float sc = tanhf(acc + b_lin[0]);
      if (lane == 0) scores[t] = sc;
    }
  }
  grid_barrier(garr, ggen, 1u);

  // ---- phase B: softmax over time (block 0 only) ----
  if (b == 0) {
    float s0 = scores[tid];
    float s1 = scores[tid + 1024];
    float m = fmaxf(s0, s1);
    m = wave_max(m);
    if (lane == 0) sbuf[wv] = m;
    __syncthreads();
    if (tid == 0) {
      float M = sbuf[0];
      for (int k = 1; k < 16; ++k) M = fmaxf(M, sbuf[k]);
      sbuf[16] = M;
    }
    __syncthreads();
    float M = sbuf[16];
    float p0 = expf(s0 - M), p1 = expf(s1 - M);
    pbuf[tid] = p0;
    pbuf[tid + 1024] = p1;
    float ssum = wave_sum(p0 + p1);
    __syncthreads();
    if (lane == 0) sbuf[wv] = ssum;
    __syncthreads();
    if (tid == 0) {
      float S = 0.0f;
      for (int k = 0; k < 16; ++k) S += sbuf[k];
      red[0] = 1.0f / ((float)TT * S);
    }
  }
  grid_barrier(garr, ggen, 2u);

  // ---- phase C: out[j] = scale * sum_t p_t * h4T[j][t] ----
  {
    const int gw = b * WPB + wv;
    if (gw < HH) {
      const float scale = red[0];
      const float* hr = h4T + (size_t)gw * TT + lane * 32;
      const float* pr = pbuf + lane * 32;
      float acc = 0.0f;
#pragma unroll
      for (int m = 0; m < 32; ++m) acc = fmaf(hr[m], pr[m], acc);
      acc = wave_sum(acc);
      if (lane == 0) out[gw] = scale * acc;
    }
  }
}

extern "C" void kernel_launch(void* const* d_in, const int* in_sizes, int n_in,
                              void* d_out, int out_size, void* d_ws, size_t ws_size,
                              hipStream_t stream) {
  hipFuncSetAttribute((const void*)lstm_pipe,
                      hipFuncAttributeMaxDynamicSharedMemorySize, 131072);
  hipMemsetAsync(d_ws, 0, 4096, stream);  // zero sync counters
  lstm_pipe<<<dim3(NBLK), dim3(1024), 131072, stream>>>(
      (const float*)d_in[0],
      (const float*)d_in[1], (const float*)d_in[2],
      (const float*)d_in[3], (const float*)d_in[4],
      (const float*)d_in[5], (const float*)d_in[6],
      (const float*)d_in[7], (const float*)d_in[8],
      (const float*)d_in[9], (const float*)d_in[10],
      (float*)d_out, (float*)d_ws);
}

// Round 9
// 7515.434 us; speedup vs baseline: 1.6165x; 1.6165x over previous
//
#include <hip/hip_runtime.h>
#include <math.h>

#define TT 2048
#define II 64
#define HH 512
#define LL 5
#define RING 64
#define BPL 32                // blocks per layer
#define NBLK (LL * BPL)       // 160
#define WPB 16                // waves per block
#define SPIN_LIMIT 2000000L

typedef unsigned long long u64;
typedef unsigned u32;

__device__ __forceinline__ float wave_sum(float v) {
#pragma unroll
  for (int m = 32; m > 0; m >>= 1) v += __shfl_xor(v, m, 64);
  return v;
}

__device__ __forceinline__ float wave_max(float v) {
#pragma unroll
  for (int m = 32; m > 0; m >>= 1) v = fmaxf(v, __shfl_xor(v, m, 64));
  return v;
}

__device__ __forceinline__ float sigmoidf_(float v) {
  return 1.0f / (1.0f + expf(-v));
}

// MALL-coherent (agent-scope relaxed) accessors — proven transport (r3/r5/r7)
__device__ __forceinline__ u32 ld4(const u32* p) {
  return __hip_atomic_load((u32*)p, __ATOMIC_RELAXED, __HIP_MEMORY_SCOPE_AGENT);
}
__device__ __forceinline__ void st4(u32* p, u32 v) {
  __hip_atomic_store(p, v, __ATOMIC_RELAXED, __HIP_MEMORY_SCOPE_AGENT);
}
__device__ __forceinline__ u64 ld8(const u64* p) {
  return __hip_atomic_load((u64*)p, __ATOMIC_RELAXED, __HIP_MEMORY_SCOPE_AGENT);
}
__device__ __forceinline__ void st8(u64* p, u64 v) {
  __hip_atomic_store(p, v, __ATOMIC_RELAXED, __HIP_MEMORY_SCOPE_AGENT);
}

// 2-deep staggered poll. Global loads complete in issue order per thread, so
// with 2 in flight the checked sample is at most 1 sample stale and samples
// land ~RTT/2 apart (vs RTT for the dependent-chain single poll).
__device__ __forceinline__ float poll_ring(const u64* p, u32 want) {
  u64 a = ld8(p);   // older sample
  u64 b = ld8(p);   // newer sample (in flight while we check a)
  long sp = 0;
  while ((u32)(a >> 32) != want) {
    a = b;          // promote newer
    b = ld8(p);     // keep one in flight
    if (++sp > SPIN_LIMIT) { a = ((u64)want << 32); break; }  // degrade, no hang
  }
  return __uint_as_float((u32)a);
}

__device__ __forceinline__ void wait_ge(u32* p, u32 v) {
  long spins = 0;
  while (ld4(p) < v) {
    if (++spins > SPIN_LIMIT) {
      __hip_atomic_fetch_max(p, v, __ATOMIC_RELAXED, __HIP_MEMORY_SCOPE_AGENT);
      break;
    }
  }
}

// Monotone full-grid barrier — readout phase transitions only (3 uses).
__device__ __forceinline__ void grid_barrier(u32* arrive, u32* gen, u32 idx) {
  __syncthreads();
  if (threadIdx.x == 0) {
    __threadfence();  // release
    u32 target = (u32)NBLK * (idx + 1u);
    u32 prev = __hip_atomic_fetch_add(arrive, 1u, __ATOMIC_RELAXED, __HIP_MEMORY_SCOPE_AGENT);
    if (prev + 1u == target) {
      __hip_atomic_store(gen, idx + 1u, __ATOMIC_RELAXED, __HIP_MEMORY_SCOPE_AGENT);
    } else {
      wait_ge(gen, idx + 1u);
    }
    __threadfence();  // acquire
  }
  __syncthreads();
}

extern "C" __global__ void __launch_bounds__(1024)
__attribute__((amdgpu_waves_per_eu(4, 4)))
lstm_pipe(
    const float* __restrict__ x,
    const float* __restrict__ w_ih0, const float* __restrict__ w_hh0,
    const float* __restrict__ b_ih0, const float* __restrict__ b_hh0,
    const float* __restrict__ w_ih, const float* __restrict__ w_hh,
    const float* __restrict__ b_ih, const float* __restrict__ b_hh,
    const float* __restrict__ w_lin, const float* __restrict__ b_lin,
    float* __restrict__ out, float* __restrict__ ws) {
  extern __shared__ float wihs[];   // [WPB][4][HH] = 128 KB dynamic
  __shared__ float hbuf[HH];        // staged own-layer h_{t-1}
  __shared__ float xbuf[HH];        // staged prev-layer h_t (or x_t)
  __shared__ float sbuf[20];

  // counters (first 4 KB of ws, memset 0): prog[l] at cnt[l*64];
  // garr at cnt[320]; ggen at cnt[336]
  u32* cnt = (u32*)ws;
  u32* garr = cnt + 320;
  u32* ggen = cnt + 336;

  // tagged h ring: [LL][RING][HH] u64 — (tag=t+1)<<32 | bits(h).
  u64* ring = (u64*)((char*)ws + 4096);
  float* h4 = (float*)(ring + (size_t)LL * RING * HH);   // TT*HH
  float* h4T = h4 + (size_t)TT * HH;                     // HH*TT
  float* scores = h4T + (size_t)HH * TT;                 // TT
  float* pbuf = scores + TT;                             // TT
  float* red = pbuf + TT;                                // 1

  const int b = blockIdx.x;
  const int tid = threadIdx.x;
  const int wv = tid >> 6;
  const int lane = tid & 63;
  const int layer = b / BPL;
  const int slot = b % BPL;
  const int j = slot * WPB + wv;   // h-output owned by this wave
  const bool is_last = (layer == LL - 1);

  u32* prog_l = cnt + layer * 64;
  u32* prog_lp1 = cnt + (layer + 1) * 64;  // valid only when layer < LL-1
  u64* myring = ring + (size_t)layer * RING * HH;
  u64* prevring = ring + (size_t)(layer > 0 ? layer - 1 : 0) * RING * HH;

  // ---- weights: whh + bias in registers (proven fit at 60 VGPR); wih in LDS ----
  float whh[4][8], bias[4];
  {
    const float* WHH = (layer == 0) ? w_hh0 : (w_hh + (size_t)(layer - 1) * 4 * HH * HH);
#pragma unroll
    for (int g = 0; g < 4; ++g) {
      const int row = g * HH + j;
#pragma unroll
      for (int m = 0; m < 8; ++m) whh[g][m] = WHH[(size_t)row * HH + m * 64 + lane];
    }
    if (layer == 0) {
#pragma unroll
      for (int g = 0; g < 4; ++g) bias[g] = b_ih0[g * HH + j] + b_hh0[g * HH + j];
    } else {
      const float* BIH = b_ih + (size_t)(layer - 1) * 4 * HH;
      const float* BHH = b_hh + (size_t)(layer - 1) * 4 * HH;
#pragma unroll
      for (int g = 0; g < 4; ++g) bias[g] = BIH[g * HH + j] + BHH[g * HH + j];
    }
    // wih -> LDS, layout [jj][g][k]
    const float* WIH = (layer == 0) ? (const float*)0
                                    : (w_ih + (size_t)(layer - 1) * 4 * HH * HH);
    for (int f = tid; f < WPB * 4 * HH; f += 1024) {
      const int jj = f >> 11;          // /2048
      const int g = (f >> 9) & 3;
      const int k = f & 511;
      const int row = g * HH + slot * WPB + jj;
      float v;
      if (layer == 0) v = (k < II) ? w_ih0[(size_t)row * II + k] : 0.0f;
      else v = WIH[(size_t)row * HH + k];
      wihs[f] = v;
    }
    // pin whh/bias (defeat load-rematerialization)
#pragma unroll
    for (int g = 0; g < 4; ++g) {
#pragma unroll
      for (int m = 0; m < 8; ++m) asm volatile("" : "+v"(whh[g][m]));
      asm volatile("" : "+v"(bias[g]));
    }
  }
  __syncthreads();

  float c = 0.0f;

  // ---- recurrence: block-level LDS staging, tag-validated MALL exchange ----
  for (int t = 0; t < TT; ++t) {
    const int sl = t & (RING - 1);
    // staging: threads 0..511 pull own h_{t-1}; 512..1023 pull input h_t / x_t
    if (tid < HH) {
      if (t > 0) {
        hbuf[tid] =
            poll_ring(myring + (size_t)((t - 1) & (RING - 1)) * HH + tid, (u32)t);
      } else {
        hbuf[tid] = 0.0f;
      }
      if (tid == 0) {
        // consumption proof (prog=t means: prevring tags <= t consumed).
        // Published every 4 steps: observed prog lags true by <= 3.
        if (slot == 0 && t > 0 && (t & 3) == 0) st4(prog_l, (u32)t);
        // back-pressure: with RING=64, our store at step u destroys prev tag
        // u-63. Check every 8 steps with margin 40 (covers publish lag 3 +
        // check stride 8, far inside the 63-step slack).
        if (layer < LL - 1 && t >= 64 && (t & 7) == 0) {
          long sp = 0;
          while (ld4(prog_lp1) < (u32)(t - 40) && ++sp < SPIN_LIMIT) {}
        }
      }
    } else {
      const int k = tid - HH;
      if (layer == 0) {
        xbuf[k] = (k < II) ? x[(size_t)t * II + k] : 0.0f;
      } else {
        xbuf[k] = poll_ring(prevring + (size_t)sl * HH + k, (u32)(t + 1));
      }
    }
    __syncthreads();

    // compute — identical FMA/reduction order to r7 (absmax 0)
    float hp[8], xin[8];
#pragma unroll
    for (int m = 0; m < 8; ++m) {
      hp[m] = hbuf[m * 64 + lane];
      xin[m] = xbuf[m * 64 + lane];
    }
    float ai = 0.0f, af = 0.0f, ag = 0.0f, ao = 0.0f;
#pragma unroll
    for (int m = 0; m < 8; ++m) {
      ai = fmaf(whh[0][m], hp[m], ai);
      af = fmaf(whh[1][m], hp[m], af);
      ag = fmaf(whh[2][m], hp[m], ag);
      ao = fmaf(whh[3][m], hp[m], ao);
    }
    const float* wb = wihs + (size_t)wv * 4 * HH;
#pragma unroll
    for (int m = 0; m < 8; ++m) {
      const int o = m * 64 + lane;
      ai = fmaf(wb[0 * HH + o], xin[m], ai);
      af = fmaf(wb[1 * HH + o], xin[m], af);
      ag = fmaf(wb[2 * HH + o], xin[m], ag);
      ao = fmaf(wb[3 * HH + o], xin[m], ao);
    }
    ai = wave_sum(ai); af = wave_sum(af); ag = wave_sum(ag); ao = wave_sum(ao);
    float gi = sigmoidf_(ai + bias[0]);
    float gf = sigmoidf_(af + bias[1]);
    float gg = tanhf(ag + bias[2]);
    float go = sigmoidf_(ao + bias[3]);
    c = gf * c + gi * gg;
    float h = go * tanhf(c);

    if (lane == 0) {
      st8(myring + (size_t)sl * HH + j,
          (((u64)(u32)(t + 1)) << 32) | (u64)__float_as_uint(h));
      if (is_last) {
        h4[(size_t)t * HH + j] = h;
        h4T[(size_t)j * TT + t] = h;
      }
    }
    __syncthreads();  // protect hbuf/xbuf from next step's staging
  }

  grid_barrier(garr, ggen, 0u);

  // ---- phase A: scores[t] = tanh(h4[t] . w_lin + b_lin) ----
  {
    const int gw = b * WPB + wv;
    if (gw < TT) {
      const int t = gw;
      const float4* hp4 = (const float4*)(h4 + (size_t)t * HH + lane * 8);
      const float4* wl4 = (const float4*)(w_lin + lane * 8);
      float4 a = hp4[0], d = hp4[1], wa = wl4[0], wd = wl4[1];
      float acc = 0.0f;
      acc = fmaf(a.x, wa.x, acc); acc = fmaf(a.y, wa.y, acc);
      acc = fmaf(a.z, wa.z, acc); acc = fmaf(a.w, wa.w, acc);
      acc = fmaf(d.x, wd.x, acc); acc = fmaf(d.y, wd.y, acc);
      acc = fmaf(d.z, wd.z, acc); acc = fmaf(d.w, wd.w, acc);
      acc = wave_sum(acc);
      float sc = tanhf(acc + b_lin[0]);
      if (lane == 0) scores[t] = sc;
    }
  }
  grid_barrier(garr, ggen, 1u);

  // ---- phase B: softmax over time (block 0 only) ----
  if (b == 0) {
    float s0 = scores[tid];
    float s1 = scores[tid + 1024];
    float m = fmaxf(s0, s1);
    m = wave_max(m);
    if (lane == 0) sbuf[wv] = m;
    __syncthreads();
    if (tid == 0) {
      float M = sbuf[0];
      for (int k = 1; k < 16; ++k) M = fmaxf(M, sbuf[k]);
      sbuf[16] = M;
    }
    __syncthreads();
    float M = sbuf[16];
    float p0 = expf(s0 - M), p1 = expf(s1 - M);
    pbuf[tid] = p0;
    pbuf[tid + 1024] = p1;
    float ssum = wave_sum(p0 + p1);
    __syncthreads();
    if (lane == 0) sbuf[wv] = ssum;
    __syncthreads();
    if (tid == 0) {
      float S = 0.0f;
      for (int k = 0; k < 16; ++k) S += sbuf[k];
      red[0] = 1.0f / ((float)TT * S);
    }
  }
  grid_barrier(garr, ggen, 2u);

  // ---- phase C: out[j] = scale * sum_t p_t * h4T[j][t] ----
  {
    const int gw = b * WPB + wv;
    if (gw < HH) {
      const float scale = red[0];
      const float* hr = h4T + (size_t)gw * TT + lane * 32;
      const float* pr = pbuf + lane * 32;
      float acc = 0.0f;
#pragma unroll
      for (int m = 0; m < 32; ++m) acc = fmaf(hr[m], pr[m], acc);
      acc = wave_sum(acc);
      if (lane == 0) out[gw] = scale * acc;
    }
  }
}

extern "C" void kernel_launch(void* const* d_in, const int* in_sizes, int n_in,
                              void* d_out, int out_size, void* d_ws, size_t ws_size,
                              hipStream_t stream) {
  hipFuncSetAttribute((const void*)lstm_pipe,
                      hipFuncAttributeMaxDynamicSharedMemorySize, 131072);
  hipMemsetAsync(d_ws, 0, 4096, stream);  // zero sync counters
  lstm_pipe<<<dim3(NBLK), dim3(1024), 131072, stream>>>(
      (const float*)d_in[0],
      (const float*)d_in[1], (const float*)d_in[2],
      (const float*)d_in[3], (const float*)d_in[4],
      (const float*)d_in[5], (const float*)d_in[6],
      (const float*)d_in[7], (const float*)d_in[8],
      (const float*)d_in[9], (const float*)d_in[10],
      (float*)d_out, (float*)d_ws);
}

// Round 10
// 7464.617 us; speedup vs baseline: 1.6275x; 1.0068x over previous
//
#include <hip/hip_runtime.h>
#include <math.h>

#define TT 2048
#define II 64
#define HH 512
#define LL 5
#define RING 64
#define BPL 32                 // blocks per layer
#define NBLK 256               // 1 block/CU (128 KB LDS) => exactly 32 blocks/XCD
#define WPB 16                 // waves per block
#define SPIN_LIMIT 2000000L
#define BARRIER_SPIN 20000000L

typedef unsigned long long u64;
typedef unsigned u32;

__device__ __forceinline__ float wave_sum(float v) {
#pragma unroll
  for (int m = 32; m > 0; m >>= 1) v += __shfl_xor(v, m, 64);
  return v;
}

__device__ __forceinline__ float wave_max(float v) {
#pragma unroll
  for (int m = 32; m > 0; m >>= 1) v = fmaxf(v, __shfl_xor(v, m, 64));
  return v;
}

__device__ __forceinline__ float sigmoidf_(float v) {
  return 1.0f / (1.0f + expf(-v));
}

// MALL-coherent (agent-scope relaxed) accessors — proven transport (r3/r5/r7/r9).
// Correctness is placement-independent; placement only changes which cache
// level services them.
__device__ __forceinline__ u32 ld4(const u32* p) {
  return __hip_atomic_load((u32*)p, __ATOMIC_RELAXED, __HIP_MEMORY_SCOPE_AGENT);
}
__device__ __forceinline__ void st4(u32* p, u32 v) {
  __hip_atomic_store(p, v, __ATOMIC_RELAXED, __HIP_MEMORY_SCOPE_AGENT);
}
__device__ __forceinline__ u64 ld8(const u64* p) {
  return __hip_atomic_load((u64*)p, __ATOMIC_RELAXED, __HIP_MEMORY_SCOPE_AGENT);
}
__device__ __forceinline__ void st8(u64* p, u64 v) {
  __hip_atomic_store(p, v, __ATOMIC_RELAXED, __HIP_MEMORY_SCOPE_AGENT);
}

// 2-deep staggered poll (r9, proven): checked sample <=1 stale, period ~RTT/2.
__device__ __forceinline__ float poll_ring(const u64* p, u32 want) {
  u64 a = ld8(p);
  u64 b = ld8(p);
  long sp = 0;
  while ((u32)(a >> 32) != want) {
    a = b;
    b = ld8(p);
    if (++sp > SPIN_LIMIT) { a = ((u64)want << 32); break; }  // degrade, no hang
  }
  return __uint_as_float((u32)a);
}

__device__ __forceinline__ void wait_ge(u32* p, u32 v) {
  long spins = 0;
  while (ld4(p) < v) {
    if (++spins > BARRIER_SPIN) {
      __hip_atomic_fetch_max(p, v, __ATOMIC_RELAXED, __HIP_MEMORY_SCOPE_AGENT);
      break;
    }
  }
}

// Monotone full-grid barrier (claim handshake + readout transitions).
__device__ __forceinline__ void grid_barrier(u32* arrive, u32* gen, u32 idx) {
  __syncthreads();
  if (threadIdx.x == 0) {
    __threadfence();  // release
    u32 target = (u32)NBLK * (idx + 1u);
    u32 prev = __hip_atomic_fetch_add(arrive, 1u, __ATOMIC_RELAXED, __HIP_MEMORY_SCOPE_AGENT);
    if (prev + 1u == target) {
      __hip_atomic_store(gen, idx + 1u, __ATOMIC_RELAXED, __HIP_MEMORY_SCOPE_AGENT);
    } else {
      wait_ge(gen, idx + 1u);
    }
    __threadfence();  // acquire
  }
  __syncthreads();
}

extern "C" __global__ void __launch_bounds__(1024)
__attribute__((amdgpu_waves_per_eu(4, 4)))
lstm_pipe(
    const float* __restrict__ x,
    const float* __restrict__ w_ih0, const float* __restrict__ w_hh0,
    const float* __restrict__ b_ih0, const float* __restrict__ b_hh0,
    const float* __restrict__ w_ih, const float* __restrict__ w_hh,
    const float* __restrict__ b_ih, const float* __restrict__ b_hh,
    const float* __restrict__ w_lin, const float* __restrict__ b_lin,
    float* __restrict__ out, float* __restrict__ ws) {
  extern __shared__ float wihs[];   // [WPB][4][HH] = 128 KB dynamic
  __shared__ float hbuf[HH];        // staged own-layer h_{t-1}
  __shared__ float xbuf[HH];        // staged prev-layer h_t (or x_t)
  __shared__ float sbuf[20];
  __shared__ int s_layer, s_slot;

  // counters (first 4 KB of ws, memset 0): prog[l] at cnt[l*64];
  // garr cnt[320]; ggen cnt[336]; claims[xcd] at cnt[352+xcd*16]; flag cnt[448]
  u32* cnt = (u32*)ws;
  u32* garr = cnt + 320;
  u32* ggen = cnt + 336;
  u32* claims = cnt + 352;
  u32* flagp = cnt + 448;

  // tagged h ring: [LL][RING][HH] u64 — (tag=t+1)<<32 | bits(h).
  u64* ring = (u64*)((char*)ws + 4096);
  float* h4 = (float*)(ring + (size_t)LL * RING * HH);   // TT*HH
  float* h4T = h4 + (size_t)TT * HH;                     // HH*TT
  float* scores = h4T + (size_t)HH * TT;                 // TT
  float* pbuf = scores + TT;                             // TT
  float* red = pbuf + TT;                                // 1

  const int b = blockIdx.x;
  const int tid = threadIdx.x;
  const int wv = tid >> 6;
  const int lane = tid & 63;

  // ---- placement: claim a (layer, slot) on this block's own XCD ----
  // Layer l's 32 blocks co-resident on XCD l => self-recurrence exchange is
  // XCD-L2-local. Transport identical either way; fallback = r9 mapping.
  if (tid == 0) {
    u32 xcc = 0;
    asm volatile("s_getreg_b32 %0, hwreg(HW_REG_XCC_ID)" : "=s"(xcc));
    xcc &= 7u;
    int layer = -1, slot = 0;
    if (xcc < LL) {
      u32 idx = __hip_atomic_fetch_add(claims + xcc * 16, 1u, __ATOMIC_RELAXED,
                                       __HIP_MEMORY_SCOPE_AGENT);
      if (idx < (u32)BPL) { layer = (int)xcc; slot = (int)idx; }
    }
    s_layer = layer; s_slot = slot;
  }
  grid_barrier(garr, ggen, 0u);
  if (b == 0 && tid == 0) {
    bool ok = true;
    for (int l = 0; l < LL; ++l) ok &= (ld4(claims + l * 16) >= (u32)BPL);
    st4(flagp, ok ? 1u : 2u);
  }
  grid_barrier(garr, ggen, 1u);
  if (tid == 0 && ld4(flagp) == 2u) {  // fallback: exact r9 role mapping
    s_layer = (b < LL * BPL) ? (b / BPL) : -1;
    s_slot = (b < LL * BPL) ? (b % BPL) : 0;
  }
  __syncthreads();
  const int layer = s_layer;
  const int slot = s_slot;

  if (layer >= 0) {
    const int j = slot * WPB + wv;   // h-output owned by this wave
    const bool is_last = (layer == LL - 1);
    u32* prog_l = cnt + layer * 64;
    u32* prog_lp1 = cnt + (layer + 1) * 64;  // valid only when layer < LL-1
    u64* myring = ring + (size_t)layer * RING * HH;
    u64* prevring = ring + (size_t)(layer > 0 ? layer - 1 : 0) * RING * HH;

    // ---- weights: whh + bias in registers; wih in LDS (r9 layout) ----
    float whh[4][8], bias[4];
    {
      const float* WHH = (layer == 0) ? w_hh0 : (w_hh + (size_t)(layer - 1) * 4 * HH * HH);
#pragma unroll
      for (int g = 0; g < 4; ++g) {
        const int row = g * HH + j;
#pragma unroll
        for (int m = 0; m < 8; ++m) whh[g][m] = WHH[(size_t)row * HH + m * 64 + lane];
      }
      if (layer == 0) {
#pragma unroll
        for (int g = 0; g < 4; ++g) bias[g] = b_ih0[g * HH + j] + b_hh0[g * HH + j];
      } else {
        const float* BIH = b_ih + (size_t)(layer - 1) * 4 * HH;
        const float* BHH = b_hh + (size_t)(layer - 1) * 4 * HH;
#pragma unroll
        for (int g = 0; g < 4; ++g) bias[g] = BIH[g * HH + j] + BHH[g * HH + j];
      }
      const float* WIH = (layer == 0) ? (const float*)0
                                      : (w_ih + (size_t)(layer - 1) * 4 * HH * HH);
      for (int f = tid; f < WPB * 4 * HH; f += 1024) {
        const int jj = f >> 11;          // /2048
        const int g = (f >> 9) & 3;
        const int k = f & 511;
        const int row = g * HH + slot * WPB + jj;
        float v;
        if (layer == 0) v = (k < II) ? w_ih0[(size_t)row * II + k] : 0.0f;
        else v = WIH[(size_t)row * HH + k];
        wihs[f] = v;
      }
#pragma unroll
      for (int g = 0; g < 4; ++g) {
#pragma unroll
        for (int m = 0; m < 8; ++m) asm volatile("" : "+v"(whh[g][m]));
        asm volatile("" : "+v"(bias[g]));
      }
    }
    __syncthreads();

    float c = 0.0f;

    // ---- recurrence: identical protocol to r9 ----
    for (int t = 0; t < TT; ++t) {
      const int sl = t & (RING - 1);
      if (tid < HH) {
        if (t > 0) {
          hbuf[tid] =
              poll_ring(myring + (size_t)((t - 1) & (RING - 1)) * HH + tid, (u32)t);
        } else {
          hbuf[tid] = 0.0f;
        }
        if (tid == 0) {
          if (slot == 0 && t > 0 && (t & 3) == 0) st4(prog_l, (u32)t);
          if (layer < LL - 1 && t >= 64 && (t & 7) == 0) {
            long sp = 0;
            while (ld4(prog_lp1) < (u32)(t - 40) && ++sp < SPIN_LIMIT) {}
          }
        }
      } else {
        const int k = tid - HH;
        if (layer == 0) {
          xbuf[k] = (k < II) ? x[(size_t)t * II + k] : 0.0f;
        } else {
          xbuf[k] = poll_ring(prevring + (size_t)sl * HH + k, (u32)(t + 1));
        }
      }
      __syncthreads();

      // compute — identical FMA/reduction order to r7/r9 (absmax 0)
      float hp[8], xin[8];
#pragma unroll
      for (int m = 0; m < 8; ++m) {
        hp[m] = hbuf[m * 64 + lane];
        xin[m] = xbuf[m * 64 + lane];
      }
      float ai = 0.0f, af = 0.0f, ag = 0.0f, ao = 0.0f;
#pragma unroll
      for (int m = 0; m < 8; ++m) {
        ai = fmaf(whh[0][m], hp[m], ai);
        af = fmaf(whh[1][m], hp[m], af);
        ag = fmaf(whh[2][m], hp[m], ag);
        ao = fmaf(whh[3][m], hp[m], ao);
      }
      const float* wb = wihs + (size_t)wv * 4 * HH;
#pragma unroll
      for (int m = 0; m < 8; ++m) {
        const int o = m * 64 + lane;
        ai = fmaf(wb[0 * HH + o], xin[m], ai);
        af = fmaf(wb[1 * HH + o], xin[m], af);
        ag = fmaf(wb[2 * HH + o], xin[m], ag);
        ao = fmaf(wb[3 * HH + o], xin[m], ao);
      }
      ai = wave_sum(ai); af = wave_sum(af); ag = wave_sum(ag); ao = wave_sum(ao);
      float gi = sigmoidf_(ai + bias[0]);
      float gf = sigmoidf_(af + bias[1]);
      float gg = tanhf(ag + bias[2]);
      float go = sigmoidf_(ao + bias[3]);
      c = gf * c + gi * gg;
      float h = go * tanhf(c);

      if (lane == 0) {
        st8(myring + (size_t)sl * HH + j,
            (((u64)(u32)(t + 1)) << 32) | (u64)__float_as_uint(h));
        if (is_last) {
          h4[(size_t)t * HH + j] = h;
          h4T[(size_t)j * TT + t] = h;
        }
      }
      __syncthreads();
    }
  }

  grid_barrier(garr, ggen, 2u);

  // ---- phase A: scores[t] = tanh(h4[t] . w_lin + b_lin) ----
  {
    const int gw = b * WPB + wv;
    if (gw < TT) {
      const int t = gw;
      const float4* hp4 = (const float4*)(h4 + (size_t)t * HH + lane * 8);
      const float4* wl4 = (const float4*)(w_lin + lane * 8);
      float4 a = hp4[0], d = hp4[1], wa = wl4[0], wd = wl4[1];
      float acc = 0.0f;
      acc = fmaf(a.x, wa.x, acc); acc = fmaf(a.y, wa.y, acc);
      acc = fmaf(a.z, wa.z, acc); acc = fmaf(a.w, wa.w, acc);
      acc = fmaf(d.x, wd.x, acc); acc = fmaf(d.y, wd.y, acc);
      acc = fmaf(d.z, wd.z, acc); acc = fmaf(d.w, wd.w, acc);
      acc = wave_sum(acc);
      float sc = tanhf(acc + b_lin[0]);
      if (lane == 0) scores[t] = sc;
    }
  }
  grid_barrier(garr, ggen, 3u);

  // ---- phase B: softmax over time (block 0 only) ----
  if (b == 0) {
    float s0 = scores[tid];
    float s1 = scores[tid + 1024];
    float m = fmaxf(s0, s1);
    m = wave_max(m);
    if (lane == 0) sbuf[wv] = m;
    __syncthreads();
    if (tid == 0) {
      float M = sbuf[0];
      for (int k = 1; k < 16; ++k) M = fmaxf(M, sbuf[k]);
      sbuf[16] = M;
    }
    __syncthreads();
    float M = sbuf[16];
    float p0 = expf(s0 - M), p1 = expf(s1 - M);
    pbuf[tid] = p0;
    pbuf[tid + 1024] = p1;
    float ssum = wave_sum(p0 + p1);
    __syncthreads();
    if (lane == 0) sbuf[wv] = ssum;
    __syncthreads();
    if (tid == 0) {
      float S = 0.0f;
      for (int k = 0; k < 16; ++k) S += sbuf[k];
      red[0] = 1.0f / ((float)TT * S);
    }
  }
  grid_barrier(garr, ggen, 4u);

  // ---- phase C: out[j] = scale * sum_t p_t * h4T[j][t] ----
  {
    const int gw = b * WPB + wv;
    if (gw < HH) {
      const float scale = red[0];
      const float* hr = h4T + (size_t)gw * TT + lane * 32;
      const float* pr = pbuf + lane * 32;
      float acc = 0.0f;
#pragma unroll
      for (int m = 0; m < 32; ++m) acc = fmaf(hr[m], pr[m], acc);
      acc = wave_sum(acc);
      if (lane == 0) out[gw] = scale * acc;
    }
  }
}

extern "C" void kernel_launch(void* const* d_in, const int* in_sizes, int n_in,
                              void* d_out, int out_size, void* d_ws, size_t ws_size,
                              hipStream_t stream) {
  hipFuncSetAttribute((const void*)lstm_pipe,
                      hipFuncAttributeMaxDynamicSharedMemorySize, 131072);
  hipMemsetAsync(d_ws, 0, 4096, stream);  // zero sync/claim counters
  lstm_pipe<<<dim3(NBLK), dim3(1024), 131072, stream>>>(
      (const float*)d_in[0],
      (const float*)d_in[1], (const float*)d_in[2],
      (const float*)d_in[3], (const float*)d_in[4],
      (const float*)d_in[5], (const float*)d_in[6],
      (const float*)d_in[7], (const float*)d_in[8],
      (const float*)d_in[9], (const float*)d_in[10],
      (float*)d_out, (float*)d_ws);
}